// Round 1
// 415.234 us; speedup vs baseline: 1.1172x; 1.1172x over previous
//
#include <hip/hip_runtime.h>

// Problem constants (from reference setup_inputs):
//   x: (4,4096,1024) fp32 -> M=16384, dim=1024, hidden=4096, rank=16
//   w_fc: (4096,1024), w_proj: (1024,4096), u:(4096,16), v:(16,1024), fast_b:(16,16), gate scalar
// out: (16384,1024) fp32
//
// R1: XOR-swizzled LDS -> conflicts 1.68e7 -> 0 (time-neutral).
// R2: dbuf + vmcnt(4) prefetch -> 196 -> 189 us/gemm (small).
// R3/R4: B direct-to-register gather -> REGRESSED. Reverted.
// R5: BK=64 single-buffered 128^2 tile, 32 MFMA/barrier-pair -> 179 us/gemm (~765 TF).
// R6: 256^2 tile, 8 waves (2Mx4N), BK=64, LDS 128KB double-buffer, 4-phase
//     schedule per K-tile (T3), counted vmcnt(8) never drained to 0 in main
//     loop (T4), s_setprio around MFMA clusters (T5), chunked-bijective XCD
//     swizzle (T1). Keeps R1's proven chunk-XOR LDS swizzle (0 conflicts,
//     global_load_lds-compatible). Target: m201-class 55-62% MfmaUtil.

typedef unsigned short u16;
typedef __attribute__((ext_vector_type(8))) short short8;
typedef __attribute__((ext_vector_type(4))) float float4v;

#define M_TOK   16384
#define DIM     1024
#define HID     4096

// ---------- helpers ----------

__device__ __forceinline__ u16 f2bf(float f) {
    union { float f; unsigned u; } v; v.f = f;
    unsigned r = v.u + 0x7fffu + ((v.u >> 16) & 1u);   // RNE
    return (u16)(r >> 16);
}

__device__ __forceinline__ void gload_lds16(const u16* g, u16* l) {
    __builtin_amdgcn_global_load_lds(
        (const __attribute__((address_space(1))) void*)g,
        (__attribute__((address_space(3))) void*)l, 16, 0, 0);
}

// ---------- prologue kernels ----------

__global__ __launch_bounds__(256) void cvt_x_kernel(const float* __restrict__ x,
                                                    u16* __restrict__ y) {
    int i = (blockIdx.x * 256 + threadIdx.x) * 4;
    float4 v = *reinterpret_cast<const float4*>(x + i);
    ushort4 o;
    o.x = f2bf(v.x); o.y = f2bf(v.y); o.z = f2bf(v.z); o.w = f2bf(v.w);
    *reinterpret_cast<ushort4*>(y + i) = o;
}

__global__ __launch_bounds__(256) void adapter_T_kernel(const float* __restrict__ u,
                                                        const float* __restrict__ fb,
                                                        float* __restrict__ T) {
    int i = blockIdx.x * 256 + threadIdx.x;
    int row = i >> 4, r = i & 15;
    float s = 0.f;
#pragma unroll
    for (int k = 0; k < 16; k++) s += u[row * 16 + k] * fb[k * 16 + r];
    T[i] = s;
}

__global__ __launch_bounds__(256) void build_w1_kernel(const float* __restrict__ w,
                                                       const float* __restrict__ T,
                                                       const float* __restrict__ v,
                                                       const float* __restrict__ gate,
                                                       u16* __restrict__ W1) {
    const int row = blockIdx.x, tid = threadIdx.x;
    float s = 0.f;
#pragma unroll
    for (int jj = 0; jj < 4; jj++) s += fabsf(w[row * 1024 + tid + jj * 256]);
#pragma unroll
    for (int o = 32; o > 0; o >>= 1) s += __shfl_down(s, o, 64);
    __shared__ float red[4];
    if ((tid & 63) == 0) red[tid >> 6] = s;
    __syncthreads();
    const float scale = fmaxf((red[0] + red[1] + red[2] + red[3]) * (1.f / 1024.f), 1e-5f);
    const float g = gate[0];
    float t[16];
#pragma unroll
    for (int r = 0; r < 16; r++) t[r] = T[row * 16 + r];
#pragma unroll
    for (int jj = 0; jj < 4; jj++) {
        const int j = tid + jj * 256;
        const float wv = w[row * 1024 + j];
        float tern = rintf(wv / scale);
        tern = fminf(1.f, fmaxf(-1.f, tern));
        float ad = 0.f;
#pragma unroll
        for (int r = 0; r < 16; r++) ad += t[r] * v[r * 1024 + j];
        W1[row * 1024 + j] = f2bf(tern * scale + g * ad);
    }
}

__global__ __launch_bounds__(256) void build_w2_kernel(const float* __restrict__ w,
                                                       u16* __restrict__ W2) {
    const int row = blockIdx.x, tid = threadIdx.x;
    float s = 0.f;
#pragma unroll
    for (int jj = 0; jj < 16; jj++) s += fabsf(w[row * 4096 + tid + jj * 256]);
#pragma unroll
    for (int o = 32; o > 0; o >>= 1) s += __shfl_down(s, o, 64);
    __shared__ float red[4];
    if ((tid & 63) == 0) red[tid >> 6] = s;
    __syncthreads();
    const float scale = fmaxf((red[0] + red[1] + red[2] + red[3]) * (1.f / 4096.f), 1e-5f);
#pragma unroll
    for (int jj = 0; jj < 16; jj++) {
        const int j = tid + jj * 256;
        float tern = rintf(w[row * 4096 + j] / scale);
        tern = fminf(1.f, fmaxf(-1.f, tern));
        W2[row * 4096 + j] = f2bf(tern * scale);
    }
}

// ---------- GEMM: C[M,N] = A[M,K] @ B[N,K]^T (both bf16 row-major) ----------
// 256x256 block, 8 waves (2M x 4N), each wave 128x64 output. BK=64, LDS
// double-buffered (2 x 64 KB). Chunk q (of 2048 per tile): row=q>>3, pos=q&7;
// position p of row r holds k-chunk p^(r&7) (R1 swizzle: coalesced 128B
// staging segments + conflict-free ds_read_b128).
//
// Schedule per K-tile t (compute from buf[t&1]):
//   ph1 q(0,0): 12 ds_read (A-qr0 x2ks + B-qc0 x2ks) | bar | prio1 16 MFMA prio0 | bar
//   ph2 q(0,1):  4 ds_read (B-qc1)                   | bar | prio1 16 MFMA prio0 | bar
//   ph3 q(1,0):  8 ds_read (A-qr1, overwrites af)    | bar | prio1 16 MFMA prio0 | bar
//   ph4 q(1,1): STAGE tile t+2 -> buf[t&1] (all reads of buf done at ph3 bar);
//               prio1 16 MFMA prio0; vmcnt(8) [counted: leaves t+2's 8 loads
//               in flight, drains t+1's]; s_barrier.
// Loads for tile t+1 were issued one full tile-compute (~4 phases) before
// their wait -> near-zero stall. vmcnt never drains to 0 in steady state.
template <int N, int K, int EPI>
__global__ __launch_bounds__(512, 2) void gemm256(const u16* __restrict__ A,
                                                  const u16* __restrict__ B,
                                                  void* __restrict__ Cv) {
    constexpr int GM  = M_TOK / 256;   // 64
    constexpr int GN  = N / 256;
    constexpr int NWG = GM * GN;       // 1024 (gemm1) / 256 (gemm2); %8==0
    constexpr int NT  = K / 64;        // 16 / 64

    __shared__ alignas(16) u16 lds[2][2][256 * 64];   // 128 KiB

    const int tid  = threadIdx.x;
    const int wave = tid >> 6, lane = tid & 63;
    const int lr = lane & 15, quad = lane >> 4;
    const int wm = (wave >> 2) << 7;   // 0 / 128
    const int wn = (wave & 3) << 6;    // 0 / 64 / 128 / 192

    // T1: chunked-bijective XCD swizzle; bn-major flat id so each XCD keeps a
    // small B panel L2-resident while A panels stream (and share via L3).
    int flat = (int)blockIdx.x;
    flat = (flat & 7) * (NWG / 8) + (flat >> 3);
    const int bm = flat % GM;
    const int bn = flat / GM;

    // staging descriptors: 4 chunks/thread for A and B (2048 chunks / 512 thr)
    const u16* Ag[4]; const u16* Bg[4]; int qo[4];
#pragma unroll
    for (int c = 0; c < 4; c++) {
        const int q = tid + c * 512;            // 0..2047
        const int row = q >> 3, p = q & 7;
        const int kc = p ^ (row & 7);
        Ag[c] = A + (size_t)(bm * 256 + row) * K + kc * 8;
        Bg[c] = B + (size_t)(bn * 256 + row) * K + kc * 8;
        qo[c] = q * 8;
    }

    float4v acc[8][4];
#pragma unroll
    for (int i = 0; i < 8; i++)
#pragma unroll
        for (int j = 0; j < 4; j++) acc[i][j] = (float4v)0.0f;

    // fragment k-chunk positions (swizzled): ks=0 -> quad^(lr&7), ks=1 -> (4+quad)^(lr&7)
    const int pk0 = (quad ^ (lr & 7)) * 8;
    const int pk1 = ((4 + quad) ^ (lr & 7)) * 8;

#define STAGE(buf, k0)                                                        \
    do {                                                                      \
        u16* la_ = &lds[buf][0][0]; u16* lb_ = &lds[buf][1][0];               \
        _Pragma("unroll")                                                     \
        for (int c_ = 0; c_ < 4; c_++) gload_lds16(Ag[c_] + (k0), la_ + qo[c_]); \
        _Pragma("unroll")                                                     \
        for (int c_ = 0; c_ < 4; c_++) gload_lds16(Bg[c_] + (k0), lb_ + qo[c_]); \
    } while (0)

#define BAR()                                                                 \
    do {                                                                      \
        __builtin_amdgcn_sched_barrier(0);                                    \
        __builtin_amdgcn_s_barrier();                                         \
        __builtin_amdgcn_sched_barrier(0);                                    \
    } while (0)

    // prologue: tile0 -> buf0, tile1 -> buf1; drain tile0, leave tile1 in flight
    STAGE(0, 0);
    STAGE(1, 64);
    __builtin_amdgcn_sched_barrier(0);
    asm volatile("s_waitcnt vmcnt(8)" ::: "memory");
    __builtin_amdgcn_s_barrier();
    __builtin_amdgcn_sched_barrier(0);
    asm volatile("" ::: "memory");

    for (int t = 0; t < NT; ++t) {
        const int cur = t & 1;
        const u16* Ab = &lds[cur][0][0];
        const u16* Bb = &lds[cur][1][0];
        short8 af[4][2], b0[2][2], b1[2][2];

        // ---- phase 1: quadrant (0,0) ----
#pragma unroll
        for (int i = 0; i < 4; i++) {
            const u16* rp = Ab + (wm + i * 16 + lr) * 64;
            af[i][0] = *reinterpret_cast<const short8*>(rp + pk0);
            af[i][1] = *reinterpret_cast<const short8*>(rp + pk1);
        }
#pragma unroll
        for (int j = 0; j < 2; j++) {
            const u16* rp = Bb + (wn + j * 16 + lr) * 64;
            b0[j][0] = *reinterpret_cast<const short8*>(rp + pk0);
            b0[j][1] = *reinterpret_cast<const short8*>(rp + pk1);
        }
        BAR();
        __builtin_amdgcn_s_setprio(1);
#pragma unroll
        for (int i = 0; i < 4; i++)
#pragma unroll
            for (int j = 0; j < 2; j++)
#pragma unroll
                for (int ks = 0; ks < 2; ks++)
                    acc[i][j] = __builtin_amdgcn_mfma_f32_16x16x32_bf16(
                        af[i][ks], b0[j][ks], acc[i][j], 0, 0, 0);
        __builtin_amdgcn_s_setprio(0);
        BAR();

        // ---- phase 2: quadrant (0,1) ----
#pragma unroll
        for (int j = 0; j < 2; j++) {
            const u16* rp = Bb + (wn + 32 + j * 16 + lr) * 64;
            b1[j][0] = *reinterpret_cast<const short8*>(rp + pk0);
            b1[j][1] = *reinterpret_cast<const short8*>(rp + pk1);
        }
        BAR();
        __builtin_amdgcn_s_setprio(1);
#pragma unroll
        for (int i = 0; i < 4; i++)
#pragma unroll
            for (int j = 0; j < 2; j++)
#pragma unroll
                for (int ks = 0; ks < 2; ks++)
                    acc[i][2 + j] = __builtin_amdgcn_mfma_f32_16x16x32_bf16(
                        af[i][ks], b1[j][ks], acc[i][2 + j], 0, 0, 0);
        __builtin_amdgcn_s_setprio(0);
        BAR();

        // ---- phase 3: quadrant (1,0) ----
#pragma unroll
        for (int i = 0; i < 4; i++) {
            const u16* rp = Ab + (wm + 64 + i * 16 + lr) * 64;
            af[i][0] = *reinterpret_cast<const short8*>(rp + pk0);
            af[i][1] = *reinterpret_cast<const short8*>(rp + pk1);
        }
        BAR();
        __builtin_amdgcn_s_setprio(1);
#pragma unroll
        for (int i = 0; i < 4; i++)
#pragma unroll
            for (int j = 0; j < 2; j++)
#pragma unroll
                for (int ks = 0; ks < 2; ks++)
                    acc[4 + i][j] = __builtin_amdgcn_mfma_f32_16x16x32_bf16(
                        af[i][ks], b0[j][ks], acc[4 + i][j], 0, 0, 0);
        __builtin_amdgcn_s_setprio(0);
        BAR();

        // ---- phase 4: quadrant (1,1) — no LDS reads; stage + counted vmcnt ----
        // All reads of buf[cur] completed (lgkm-waited) by every wave before
        // ph3's closing barrier -> safe to stage tile t+2 into buf[cur] now.
        asm volatile("" ::: "memory");
        if (t + 2 < NT) {
            STAGE(cur, (t + 2) * 64);
        }
        __builtin_amdgcn_sched_barrier(0);
        __builtin_amdgcn_s_setprio(1);
#pragma unroll
        for (int i = 0; i < 4; i++)
#pragma unroll
            for (int j = 0; j < 2; j++)
#pragma unroll
                for (int ks = 0; ks < 2; ks++)
                    acc[4 + i][2 + j] = __builtin_amdgcn_mfma_f32_16x16x32_bf16(
                        af[i][ks], b1[j][ks], acc[4 + i][2 + j], 0, 0, 0);
        __builtin_amdgcn_s_setprio(0);
        __builtin_amdgcn_sched_barrier(0);
        if (t + 1 < NT) {
            if (t + 2 < NT) {
                asm volatile("s_waitcnt vmcnt(8)" ::: "memory");  // drain t+1, keep t+2 in flight
            } else {
                asm volatile("s_waitcnt vmcnt(0)" ::: "memory");  // last prefetch: full drain
            }
            __builtin_amdgcn_s_barrier();
            __builtin_amdgcn_sched_barrier(0);
            asm volatile("" ::: "memory");
        }
    }
#undef STAGE
#undef BAR

    // ---- epilogue. C/D layout: col=lane&15, row=quad*4+reg (m89/m91-verified) ----
    const int row0 = bm * 256 + wm + quad * 4;
    const int col0 = bn * 256 + wn + lr;
#pragma unroll
    for (int qr = 0; qr < 2; qr++)
#pragma unroll
        for (int i = 0; i < 4; i++)
#pragma unroll
            for (int qc = 0; qc < 2; qc++)
#pragma unroll
                for (int j = 0; j < 2; j++) {
                    const int col = col0 + qc * 32 + j * 16;
                    const float4v a = acc[qr * 4 + i][qc * 2 + j];
#pragma unroll
                    for (int r = 0; r < 4; r++) {
                        const int row = row0 + qr * 64 + i * 16 + r;
                        if (EPI == 0) {
                            const float rr = fmaxf(a[r], 0.f);
                            ((u16*)Cv)[(size_t)row * N + col] = f2bf(rr * rr);
                        } else {
                            ((float*)Cv)[(size_t)row * N + col] = a[r];
                        }
                    }
                }
}

// ---------- launch ----------

extern "C" void kernel_launch(void* const* d_in, const int* in_sizes, int n_in,
                              void* d_out, int out_size, void* d_ws, size_t ws_size,
                              hipStream_t stream) {
    const float* x      = (const float*)d_in[0];
    const float* fast_b = (const float*)d_in[1];
    const float* w_fc   = (const float*)d_in[2];
    const float* w_proj = (const float*)d_in[3];
    const float* u      = (const float*)d_in[4];
    const float* v      = (const float*)d_in[5];
    const float* gate   = (const float*)d_in[6];
    float* out = (float*)d_out;

    char* ws = (char*)d_ws;
    u16*   Xb  = (u16*)(ws + 0);                         // 16384*1024*2 = 32 MB
    u16*   W1  = (u16*)(ws + 33554432);                  // 4096*1024*2  =  8 MB
    u16*   W2  = (u16*)(ws + 41943040);                  // 1024*4096*2  =  8 MB
    u16*   RSQ = (u16*)(ws + 50331648);                  // 16384*4096*2 = 128 MB
    float* T   = (float*)(ws + 184549376);               // 4096*16*4    = 256 KB

    cvt_x_kernel<<<M_TOK * DIM / (256 * 4), 256, 0, stream>>>(x, Xb);
    adapter_T_kernel<<<HID * 16 / 256, 256, 0, stream>>>(u, fast_b, T);
    build_w1_kernel<<<HID, 256, 0, stream>>>(w_fc, T, v, gate, W1);
    build_w2_kernel<<<DIM, 256, 0, stream>>>(w_proj, W2);

    // GEMM1: (16384,1024) @ (4096,1024)^T -> relu^2 bf16 (16384,4096); 1024 wgs
    gemm256<HID, DIM, 0><<<dim3((M_TOK / 256) * (HID / 256)), 512, 0, stream>>>(Xb, W1, RSQ);
    // GEMM2: (16384,4096) @ (1024,4096)^T -> fp32 out (16384,1024); 256 wgs
    gemm256<DIM, HID, 1><<<dim3((M_TOK / 256) * (DIM / 256)), 512, 0, stream>>>(RSQ, W2, out);
}

// Round 2
// 395.239 us; speedup vs baseline: 1.1738x; 1.0506x over previous
//
#include <hip/hip_runtime.h>

// Problem constants (from reference setup_inputs):
//   x: (4,4096,1024) fp32 -> M=16384, dim=1024, hidden=4096, rank=16
//   w_fc: (4096,1024), w_proj: (1024,4096), u:(4096,16), v:(16,1024), fast_b:(16,16), gate scalar
// out: (16384,1024) fp32
//
// R1: XOR-swizzled LDS -> conflicts 1.68e7 -> 0 (time-neutral).
// R2: dbuf + vmcnt(4) prefetch -> 196 -> 189 us/gemm (small).
// R3/R4: B direct-to-register gather -> REGRESSED. Reverted.
// R5: BK=64 single-buffered 128^2 tile -> 179 us/gemm (~765 TF).
// R6: 256^2 tile, 8 waves, 4-phase lockstep schedule -> 157 us/gemm, MfmaUtil 38%.
//     Post-mortem: ds_read and MFMA segments fully SERIALIZED (lgkmcnt(0)
//     right before each cluster; matrix backlog drains before next reads).
// R7: 8 fine phases/K-tile (8 MFMA each), ONE-PHASE-AHEAD register prefetch,
//     no intra-tile barriers (compiler's counted lgkmcnt keeps new reads in
//     flight across MFMA clusters -> genuine LDS/MFMA pipe overlap). One
//     handshake per K-tile between ph6/ph7: bar -> STAGE(t+2) -> vmcnt(8)
//     -> bar -> cross-tile fragment prefetch (overlaps ph7). Prologue fused
//     into a single kernel (adapter_T inlined into build_w1).

typedef unsigned short u16;
typedef __attribute__((ext_vector_type(8))) short short8;
typedef __attribute__((ext_vector_type(4))) float float4v;

#define M_TOK   16384
#define DIM     1024
#define HID     4096

// ---------- helpers ----------

__device__ __forceinline__ u16 f2bf(float f) {
    union { float f; unsigned u; } v; v.f = f;
    unsigned r = v.u + 0x7fffu + ((v.u >> 16) & 1u);   // RNE
    return (u16)(r >> 16);
}

__device__ __forceinline__ void gload_lds16(const u16* g, u16* l) {
    __builtin_amdgcn_global_load_lds(
        (const __attribute__((address_space(1))) void*)g,
        (__attribute__((address_space(3))) void*)l, 16, 0, 0);
}

// ---------- fused prologue kernel ----------
// blocks [0, HID)           : build W1 row b   (adapter T inlined)
// blocks [HID, HID+DIM)     : build W2 row b-HID
// blocks [HID+DIM, +16384)  : cvt x -> bf16

__global__ __launch_bounds__(256) void prologue_kernel(
    const float* __restrict__ x, const float* __restrict__ w_fc,
    const float* __restrict__ w_proj, const float* __restrict__ u,
    const float* __restrict__ fb, const float* __restrict__ v,
    const float* __restrict__ gate,
    u16* __restrict__ Xb, u16* __restrict__ W1, u16* __restrict__ W2) {
    const int b = blockIdx.x, tid = threadIdx.x;
    __shared__ float red[4];

    if (b < HID) {
        // ---- build_w1, row = b ----
        const int row = b;
        float s = 0.f;
#pragma unroll
        for (int jj = 0; jj < 4; jj++) s += fabsf(w_fc[row * 1024 + tid + jj * 256]);
#pragma unroll
        for (int o = 32; o > 0; o >>= 1) s += __shfl_down(s, o, 64);
        if ((tid & 63) == 0) red[tid >> 6] = s;
        __syncthreads();
        const float scale = fmaxf((red[0] + red[1] + red[2] + red[3]) * (1.f / 1024.f), 1e-5f);
        const float g = gate[0];
        // adapter T inlined: t[r] = sum_k u[row,k] * fb[k,r]  (same k-order as before)
        float t[16];
#pragma unroll
        for (int r = 0; r < 16; r++) t[r] = 0.f;
#pragma unroll
        for (int k = 0; k < 16; k++) {
            const float uk = u[row * 16 + k];
#pragma unroll
            for (int r = 0; r < 16; r++) t[r] += uk * fb[k * 16 + r];
        }
#pragma unroll
        for (int jj = 0; jj < 4; jj++) {
            const int j = tid + jj * 256;
            const float wv = w_fc[row * 1024 + j];
            float tern = rintf(wv / scale);
            tern = fminf(1.f, fmaxf(-1.f, tern));
            float ad = 0.f;
#pragma unroll
            for (int r = 0; r < 16; r++) ad += t[r] * v[r * 1024 + j];
            W1[row * 1024 + j] = f2bf(tern * scale + g * ad);
        }
    } else if (b < HID + DIM) {
        // ---- build_w2, row = b - HID ----
        const int row = b - HID;
        float s = 0.f;
#pragma unroll
        for (int jj = 0; jj < 16; jj++) s += fabsf(w_proj[row * 4096 + tid + jj * 256]);
#pragma unroll
        for (int o = 32; o > 0; o >>= 1) s += __shfl_down(s, o, 64);
        if ((tid & 63) == 0) red[tid >> 6] = s;
        __syncthreads();
        const float scale = fmaxf((red[0] + red[1] + red[2] + red[3]) * (1.f / 4096.f), 1e-5f);
#pragma unroll
        for (int jj = 0; jj < 16; jj++) {
            const int j = tid + jj * 256;
            float tern = rintf(w_proj[row * 4096 + j] / scale);
            tern = fminf(1.f, fmaxf(-1.f, tern));
            W2[row * 4096 + j] = f2bf(tern * scale);
        }
    } else {
        // ---- cvt_x ----
        const int i = (b - (HID + DIM)) * 1024 + tid * 4;
        float4 vv = *reinterpret_cast<const float4*>(x + i);
        ushort4 o;
        o.x = f2bf(vv.x); o.y = f2bf(vv.y); o.z = f2bf(vv.z); o.w = f2bf(vv.w);
        *reinterpret_cast<ushort4*>(Xb + i) = o;
    }
}

// ---------- GEMM: C[M,N] = A[M,K] @ B[N,K]^T (both bf16 row-major) ----------
// 256x256 block, 8 waves (2M x 4N), each wave 128x64. BK=64, LDS dbuf 2x64KB.
// Chunk q (of 2048/tile): row=q>>3, pos=q&7; position p of row r holds k-chunk
// p^(r&7) (coalesced 128B staging segments, conflict-free ds_read_b128).
//
// 8 fine phases per K-tile, one-phase-ahead register prefetch, no intra-tile
// barriers. Fragment sets: even (A0,A1,B0,B1 = k-step 0), odd (C0,C1,D0,D1 =
// k-step 1). Reads issued 1-2 phases before use; compiler emits counted
// lgkmcnt so reads stay in flight under the previous MFMA cluster.
template <int N, int K, int EPI>
__global__ __launch_bounds__(512, 2) void gemm256(const u16* __restrict__ A,
                                                  const u16* __restrict__ B,
                                                  void* __restrict__ Cv) {
    constexpr int GM  = M_TOK / 256;   // 64
    constexpr int GN  = N / 256;
    constexpr int NWG = GM * GN;       // %8==0
    constexpr int NT  = K / 64;

    __shared__ alignas(16) u16 lds[2][2][256 * 64];   // 128 KiB

    const int tid  = threadIdx.x;
    const int wave = tid >> 6, lane = tid & 63;
    const int lr = lane & 15, quad = lane >> 4;
    const int wm = (wave >> 2) << 7;   // 0 / 128
    const int wn = (wave & 3) << 6;    // 0..192

    // T1 chunked-bijective XCD swizzle (NWG % 8 == 0)
    int flat = (int)blockIdx.x;
    flat = (flat & 7) * (NWG / 8) + (flat >> 3);
    const int bm = flat % GM;
    const int bn = flat / GM;

    // staging descriptors: 4 chunks/thread for A and B
    const u16* Ag[4]; const u16* Bg[4]; int qo[4];
#pragma unroll
    for (int c = 0; c < 4; c++) {
        const int q = tid + c * 512;            // 0..2047
        const int row = q >> 3, p = q & 7;
        const int kc = p ^ (row & 7);
        Ag[c] = A + (size_t)(bm * 256 + row) * K + kc * 8;
        Bg[c] = B + (size_t)(bn * 256 + row) * K + kc * 8;
        qo[c] = q * 8;
    }

    float4v acc[8][4];
#pragma unroll
    for (int i = 0; i < 8; i++)
#pragma unroll
        for (int j = 0; j < 4; j++) acc[i][j] = (float4v)0.0f;

    // fragment addressing: elem off = (wrow+lr+16*i)*64 + pk[ks]
    const int pk0 = (quad ^ (lr & 7)) * 8;          // k-step 0 chunk pos
    const int pk1 = ((4 + quad) ^ (lr & 7)) * 8;    // k-step 1 chunk pos
    const int aoff = (wm + lr) * 64;
    const int boff = (wn + lr) * 64;

#define STAGE(buf, k0)                                                        \
    do {                                                                      \
        u16* la_ = &lds[buf][0][0]; u16* lb_ = &lds[buf][1][0];               \
        _Pragma("unroll")                                                     \
        for (int c_ = 0; c_ < 4; c_++) gload_lds16(Ag[c_] + (k0), la_ + qo[c_]); \
        _Pragma("unroll")                                                     \
        for (int c_ = 0; c_ < 4; c_++) gload_lds16(Bg[c_] + (k0), lb_ + qo[c_]); \
    } while (0)

#define SB() __builtin_amdgcn_sched_barrier(0)

#define CLUSTER8(ri, cj, Af, Bf)                                              \
    do {                                                                      \
        SB();                                                                 \
        __builtin_amdgcn_s_setprio(1);                                        \
        _Pragma("unroll")                                                     \
        for (int i_ = 0; i_ < 4; i_++) {                                      \
            acc[(ri) + i_][(cj) + 0] = __builtin_amdgcn_mfma_f32_16x16x32_bf16( \
                Af[i_], Bf[0], acc[(ri) + i_][(cj) + 0], 0, 0, 0);            \
            acc[(ri) + i_][(cj) + 1] = __builtin_amdgcn_mfma_f32_16x16x32_bf16( \
                Af[i_], Bf[1], acc[(ri) + i_][(cj) + 1], 0, 0, 0);            \
        }                                                                     \
        __builtin_amdgcn_s_setprio(0);                                        \
        SB();                                                                 \
    } while (0)

    short8 A0[4], A1[4], B0v[2], B1v[2];   // even set (k-step 0 of tile)
    short8 C0[4], C1[4], D0v[2], D1v[2];   // odd  set (k-step 1 of tile)

    // ---- prologue: stage tile0->buf0, tile1->buf1; preload S0 from buf0 ----
    STAGE(0, 0);
    STAGE(1, 64);
    SB();
    asm volatile("s_waitcnt vmcnt(8)" ::: "memory");   // tile0 landed
    __builtin_amdgcn_s_barrier();
    SB();
    {
        const u16* Ab = &lds[0][0][0]; const u16* Bb = &lds[0][1][0];
#pragma unroll
        for (int i = 0; i < 4; i++) A0[i]  = *reinterpret_cast<const short8*>(Ab + aoff + 1024 * i + pk0);
#pragma unroll
        for (int j = 0; j < 2; j++) B0v[j] = *reinterpret_cast<const short8*>(Bb + boff + 1024 * j + pk0);
    }

    for (int t = 0; t < NT; ++t) {
        const int cur = t & 1, nxt = cur ^ 1;
        const u16* Ab = &lds[cur][0][0];
        const u16* Bb = &lds[cur][1][0];

        // ph0: issue B1e (cols wn+32..63, ks0); mfma A0*B0 -> acc[0..3][0..1]
#pragma unroll
        for (int j = 0; j < 2; j++) B1v[j] = *reinterpret_cast<const short8*>(Bb + boff + 2048 + 1024 * j + pk0);
        CLUSTER8(0, 0, A0, B0v);

        // ph1: issue A1e (rows wm+64.., ks0); mfma A0*B1 -> acc[0..3][2..3]
#pragma unroll
        for (int i = 0; i < 4; i++) A1[i] = *reinterpret_cast<const short8*>(Ab + aoff + 4096 + 1024 * i + pk0);
        CLUSTER8(0, 2, A0, B1v);

        // ph2: issue A0o (rows wm.., ks1); mfma A1*B0 -> acc[4..7][0..1]
#pragma unroll
        for (int i = 0; i < 4; i++) C0[i] = *reinterpret_cast<const short8*>(Ab + aoff + 1024 * i + pk1);
        CLUSTER8(4, 0, A1, B0v);

        // ph3: issue B0o; mfma A1*B1 -> acc[4..7][2..3]
#pragma unroll
        for (int j = 0; j < 2; j++) D0v[j] = *reinterpret_cast<const short8*>(Bb + boff + 1024 * j + pk1);
        CLUSTER8(4, 2, A1, B1v);

        // ph4: issue B1o; mfma C0*D0 -> acc[0..3][0..1]
#pragma unroll
        for (int j = 0; j < 2; j++) D1v[j] = *reinterpret_cast<const short8*>(Bb + boff + 2048 + 1024 * j + pk1);
        CLUSTER8(0, 0, C0, D0v);

        // ph5: issue A1o; mfma C0*D1 -> acc[0..3][2..3]
#pragma unroll
        for (int i = 0; i < 4; i++) C1[i] = *reinterpret_cast<const short8*>(Ab + aoff + 4096 + 1024 * i + pk1);
        CLUSTER8(0, 2, C0, D1v);

        // ph6: mfma C1*D0 -> acc[4..7][0..1]   (no reads; all tile reads done
        // after the compiler's lgkm wait for C1 before this cluster)
        CLUSTER8(4, 0, C1, D0v);

        // ---- per-tile handshake (between ph6 and ph7) ----
        SB();
        __builtin_amdgcn_s_barrier();            // (1) all waves done reading buf[cur]
        SB();
        if (t + 2 < NT) STAGE(cur, (t + 2) * 64);
        SB();
        if (t + 1 < NT) {
            if (t + 2 < NT) {
                asm volatile("s_waitcnt vmcnt(8)" ::: "memory");  // drain t+1, keep t+2
            } else {
                asm volatile("s_waitcnt vmcnt(0)" ::: "memory");  // last prefetch
            }
            SB();
            __builtin_amdgcn_s_barrier();        // (2) buf[nxt] valid for all waves
            SB();
            // cross-tile prefetch S0' (overlaps ph7's MFMAs)
            const u16* An = &lds[nxt][0][0]; const u16* Bn = &lds[nxt][1][0];
#pragma unroll
            for (int i = 0; i < 4; i++) A0[i]  = *reinterpret_cast<const short8*>(An + aoff + 1024 * i + pk0);
#pragma unroll
            for (int j = 0; j < 2; j++) B0v[j] = *reinterpret_cast<const short8*>(Bn + boff + 1024 * j + pk0);
        }

        // ph7: mfma C1*D1 -> acc[4..7][2..3]
        CLUSTER8(4, 2, C1, D1v);
    }
#undef STAGE
#undef SB
#undef CLUSTER8

    // ---- epilogue. C/D layout: col=lane&15, row=quad*4+reg (m89/m91-verified) ----
    const int row0 = bm * 256 + wm + quad * 4;
    const int col0 = bn * 256 + wn + lr;
#pragma unroll
    for (int qr = 0; qr < 2; qr++)
#pragma unroll
        for (int i = 0; i < 4; i++)
#pragma unroll
            for (int qc = 0; qc < 2; qc++)
#pragma unroll
                for (int j = 0; j < 2; j++) {
                    const int col = col0 + qc * 32 + j * 16;
                    const float4v a = acc[qr * 4 + i][qc * 2 + j];
#pragma unroll
                    for (int r = 0; r < 4; r++) {
                        const int row = row0 + qr * 64 + i * 16 + r;
                        if (EPI == 0) {
                            const float rr = fmaxf(a[r], 0.f);
                            ((u16*)Cv)[(size_t)row * N + col] = f2bf(rr * rr);
                        } else {
                            ((float*)Cv)[(size_t)row * N + col] = a[r];
                        }
                    }
                }
}

// ---------- launch ----------

extern "C" void kernel_launch(void* const* d_in, const int* in_sizes, int n_in,
                              void* d_out, int out_size, void* d_ws, size_t ws_size,
                              hipStream_t stream) {
    const float* x      = (const float*)d_in[0];
    const float* fast_b = (const float*)d_in[1];
    const float* w_fc   = (const float*)d_in[2];
    const float* w_proj = (const float*)d_in[3];
    const float* u      = (const float*)d_in[4];
    const float* v      = (const float*)d_in[5];
    const float* gate   = (const float*)d_in[6];
    float* out = (float*)d_out;

    char* ws = (char*)d_ws;
    u16*   Xb  = (u16*)(ws + 0);                         // 16384*1024*2 = 32 MB
    u16*   W1  = (u16*)(ws + 33554432);                  // 4096*1024*2  =  8 MB
    u16*   W2  = (u16*)(ws + 41943040);                  // 1024*4096*2  =  8 MB
    u16*   RSQ = (u16*)(ws + 50331648);                  // 16384*4096*2 = 128 MB

    // fused prologue: W1 rows | W2 rows | x conversion
    prologue_kernel<<<HID + DIM + M_TOK * DIM / (256 * 4), 256, 0, stream>>>(
        x, w_fc, w_proj, u, fast_b, v, gate, Xb, W1, W2);

    // GEMM1: (16384,1024) @ (4096,1024)^T -> relu^2 bf16 (16384,4096); 1024 wgs
    gemm256<HID, DIM, 0><<<dim3((M_TOK / 256) * (HID / 256)), 512, 0, stream>>>(Xb, W1, RSQ);
    // GEMM2: (16384,4096) @ (1024,4096)^T -> fp32 out (16384,1024); 256 wgs
    gemm256<DIM, HID, 1><<<dim3((M_TOK / 256) * (DIM / 256)), 512, 0, stream>>>(RSQ, W2, out);
}

// Round 5
// 395.187 us; speedup vs baseline: 1.1739x; 1.0001x over previous
//
#include <hip/hip_runtime.h>

// Problem constants (from reference setup_inputs):
//   x: (4,4096,1024) fp32 -> M=16384, dim=1024, hidden=4096, rank=16
//   w_fc: (4096,1024), w_proj: (1024,4096), u:(4096,16), v:(16,1024), fast_b:(16,16), gate scalar
// out: (16384,1024) fp32
//
// R1: XOR-swizzled LDS -> conflicts 1.68e7 -> 0 (time-neutral).
// R2: dbuf + vmcnt(4) prefetch -> 196 -> 189 us/gemm (small).
// R3/R4: B direct-to-register gather -> REGRESSED. Reverted.
// R5: BK=64 single-buffered 128^2 tile -> 179 us/gemm (~765 TF).
// R6: 256^2 tile, 8 waves, 4-phase lockstep -> 157 us/gemm, MfmaUtil 38%.
// R7: barrier-free one-phase-ahead reg prefetch -> 151.5 us/gemm, MfmaUtil 37%.
// R8: m201 8-phase port. UNMEASURED (container failed 2x); audit found a real
//     race in the final iteration's ph4 vmcnt(4).
// R9: race fixed (vmcnt(0) when the phase-pair staged nothing). UNMEASURED
//     (container failed 2x again; no timing block -> bench never executed;
//     full FIFO ledger re-audit found no hang/fault vector).
// R10: R9 resubmission with barriers switched from raw asm("s_barrier") to
//     __builtin_amdgcn_s_barrier() (the HW-verified m201 form; identical
//     ISA) bracketed by compiler-only memory fences. No semantic change.

typedef unsigned short u16;
typedef __attribute__((ext_vector_type(8))) short short8;
typedef __attribute__((ext_vector_type(4))) float float4v;

#define M_TOK   16384
#define DIM     1024
#define HID     4096

// ---------- helpers ----------

__device__ __forceinline__ u16 f2bf(float f) {
    union { float f; unsigned u; } v; v.f = f;
    unsigned r = v.u + 0x7fffu + ((v.u >> 16) & 1u);   // RNE
    return (u16)(r >> 16);
}

__device__ __forceinline__ void gload_lds16(const u16* g, u16* l) {
    __builtin_amdgcn_global_load_lds(
        (const __attribute__((address_space(1))) void*)g,
        (__attribute__((address_space(3))) void*)l, 16, 0, 0);
}

// ---------- fused prologue kernel ----------
// blocks [0, HID)           : build W1 row b   (adapter T inlined)
// blocks [HID, HID+DIM)     : build W2 row b-HID
// blocks [HID+DIM, +16384)  : cvt x -> bf16

__global__ __launch_bounds__(256) void prologue_kernel(
    const float* __restrict__ x, const float* __restrict__ w_fc,
    const float* __restrict__ w_proj, const float* __restrict__ u,
    const float* __restrict__ fb, const float* __restrict__ v,
    const float* __restrict__ gate,
    u16* __restrict__ Xb, u16* __restrict__ W1, u16* __restrict__ W2) {
    const int b = blockIdx.x, tid = threadIdx.x;
    __shared__ float red[4];

    if (b < HID) {
        // ---- build_w1, row = b ----
        const int row = b;
        float s = 0.f;
#pragma unroll
        for (int jj = 0; jj < 4; jj++) s += fabsf(w_fc[row * 1024 + tid + jj * 256]);
#pragma unroll
        for (int o = 32; o > 0; o >>= 1) s += __shfl_down(s, o, 64);
        if ((tid & 63) == 0) red[tid >> 6] = s;
        __syncthreads();
        const float scale = fmaxf((red[0] + red[1] + red[2] + red[3]) * (1.f / 1024.f), 1e-5f);
        const float g = gate[0];
        float t[16];
#pragma unroll
        for (int r = 0; r < 16; r++) t[r] = 0.f;
#pragma unroll
        for (int k = 0; k < 16; k++) {
            const float uk = u[row * 16 + k];
#pragma unroll
            for (int r = 0; r < 16; r++) t[r] += uk * fb[k * 16 + r];
        }
#pragma unroll
        for (int jj = 0; jj < 4; jj++) {
            const int j = tid + jj * 256;
            const float wv = w_fc[row * 1024 + j];
            float tern = rintf(wv / scale);
            tern = fminf(1.f, fmaxf(-1.f, tern));
            float ad = 0.f;
#pragma unroll
            for (int r = 0; r < 16; r++) ad += t[r] * v[r * 1024 + j];
            W1[row * 1024 + j] = f2bf(tern * scale + g * ad);
        }
    } else if (b < HID + DIM) {
        // ---- build_w2, row = b - HID ----
        const int row = b - HID;
        float s = 0.f;
#pragma unroll
        for (int jj = 0; jj < 16; jj++) s += fabsf(w_proj[row * 4096 + tid + jj * 256]);
#pragma unroll
        for (int o = 32; o > 0; o >>= 1) s += __shfl_down(s, o, 64);
        if ((tid & 63) == 0) red[tid >> 6] = s;
        __syncthreads();
        const float scale = fmaxf((red[0] + red[1] + red[2] + red[3]) * (1.f / 4096.f), 1e-5f);
#pragma unroll
        for (int jj = 0; jj < 16; jj++) {
            const int j = tid + jj * 256;
            float tern = rintf(w_proj[row * 4096 + j] / scale);
            tern = fminf(1.f, fmaxf(-1.f, tern));
            W2[row * 4096 + j] = f2bf(tern * scale);
        }
    } else {
        // ---- cvt_x ----
        const int i = (b - (HID + DIM)) * 1024 + tid * 4;
        float4 vv = *reinterpret_cast<const float4*>(x + i);
        ushort4 o;
        o.x = f2bf(vv.x); o.y = f2bf(vv.y); o.z = f2bf(vv.z); o.w = f2bf(vv.w);
        *reinterpret_cast<ushort4*>(Xb + i) = o;
    }
}

// ---------- GEMM: C[M,N] = A[M,K] @ B[N,K]^T (both bf16 row-major) ----------
// 256x256 block, 8 waves (2M x 4N), per-wave 128x64. BK=64, LDS 2x(A+B) dbuf
// = 128 KiB. Chunk q (of 2048/tile): row=q>>3, pos=q&7; pos p of row r holds
// k-chunk p^(r&7) (coalesced 128B staging, conflict-free ds_read_b128).
//
// 8-phase iteration = 2 K-tiles (t0=2it in buf0, t1=2it+1 in buf1).
// Phase p: [reads | 1 half-tile stage (2 gload_lds) | (lgkm8 if 12 reads) |
//           barrier | lgkm0 | setprio1 16 MFMA setprio0 | barrier]
//   ph1 Q0(t0): rd Alo+Blo(12); stage b1.Ah0<-t1
//   ph2 Q1(t0): rd Bhi(4);      stage b1.Ah1<-t1
//   ph3 Q2(t0): rd Ahi(8);      stage b0.Bh0<-t0+2
//   ph4 Q3(t0): rd none;        stage b0.Bh1<-t0+2; vmcnt(4|0*)
//   ph5 Q0(t1): rd Alo+Blo(12); stage b0.Ah0<-t0+2
//   ph6 Q1(t1): rd Bhi(4);      stage b0.Ah1<-t0+2
//   ph7 Q2(t1): rd Ahi(8);      stage b1.Bh0<-t1+2
//   ph8 Q3(t1): rd none;        stage b1.Bh1<-t1+2; vmcnt(4|0*)
// (*) vmcnt(4) is only sound when THIS phase pair staged (the 4 newest
// in-flight loads are then ph3/4's resp. ph7/8's own); in the final
// iteration those stages are skipped, so the wait must be vmcnt(0).
// FIFO ledger (steady ph4): outstanding = {b1.Bh* <=4, b1.Ah0 2, b1.Ah1 2,
// b0.Bh0' 2, b0.Bh1' 2}; vmcnt(4) retires all but newest 4 -> buf1 fully
// landed before ph5. Symmetric at ph8 for buf0@t0+2 before next ph1.
// Write-safety: each region's last ds_read drains at that phase's lgkm0,
// >=1 closing barrier before its re-stage. Prologue: 6 half-stages +
// vmcnt(4) -> b0 landed, b1.Bh* in flight (covered by it0.ph4 wait).
// NT even (16/64). All barriers block-uniform.
template <int N, int K, int EPI>
__global__ __launch_bounds__(512, 2) void gemm256(const u16* __restrict__ A,
                                                  const u16* __restrict__ B,
                                                  void* __restrict__ Cv) {
    constexpr int GM  = M_TOK / 256;   // 64
    constexpr int GN  = N / 256;
    constexpr int NWG = GM * GN;       // %8==0
    constexpr int NT  = K / 64;        // 16 / 64 (even)

    __shared__ alignas(16) u16 lds[2][2][256 * 64];   // 128 KiB

    const int tid  = threadIdx.x;
    const int wave = tid >> 6, lane = tid & 63;
    const int lr = lane & 15, quad = lane >> 4;
    const int wm = (wave >> 2) << 7;   // 0 / 128
    const int wn = (wave & 3) << 6;    // 0..192

    // T1 chunked-bijective XCD swizzle (NWG % 8 == 0)
    int flat = (int)blockIdx.x;
    flat = (flat & 7) * (NWG / 8) + (flat >> 3);
    const int bm = flat % GM;
    const int bn = flat / GM;

    // staging descriptors: 4 chunks/thread for A and B; chunks c={2h,2h+1}
    // cover rows [h*128,(h+1)*128) = half h.
    const u16* Ag[4]; const u16* Bg[4]; int qo[4];
#pragma unroll
    for (int c = 0; c < 4; c++) {
        const int q = tid + c * 512;            // 0..2047
        const int row = q >> 3, p = q & 7;
        const int kc = p ^ (row & 7);
        Ag[c] = A + (size_t)(bm * 256 + row) * K + kc * 8;
        Bg[c] = B + (size_t)(bn * 256 + row) * K + kc * 8;
        qo[c] = q * 8;
    }

    float4v acc[8][4];
#pragma unroll
    for (int i = 0; i < 8; i++)
#pragma unroll
        for (int j = 0; j < 4; j++) acc[i][j] = (float4v)0.0f;

    // fragment addressing: elem off = (wrow+lr+16*i)*64 + pk[ks]
    const int pk0 = (quad ^ (lr & 7)) * 8;          // k-step 0 chunk pos
    const int pk1 = ((4 + quad) ^ (lr & 7)) * 8;    // k-step 1 chunk pos
    const int aoff = (wm + lr) * 64;
    const int boff = (wn + lr) * 64;

#define CFENCE() asm volatile("" ::: "memory")
#define BARX()  do { CFENCE(); __builtin_amdgcn_s_barrier(); CFENCE(); } while (0)
#define WLG0()  asm volatile("s_waitcnt lgkmcnt(0)" ::: "memory")
#define WLG8()  asm volatile("s_waitcnt lgkmcnt(8)" ::: "memory")
#define WVM4()  asm volatile("s_waitcnt vmcnt(4)" ::: "memory")
#define WVM0()  asm volatile("s_waitcnt vmcnt(0)" ::: "memory")

#define STAGE_HALF(buf, mat, h, k0)                                           \
    do {                                                                      \
        u16* lp_ = &lds[buf][mat][0];                                         \
        gload_lds16(((mat) == 0 ? Ag[2*(h)]   : Bg[2*(h)])   + (k0),          \
                    lp_ + qo[2*(h)]);                                         \
        gload_lds16(((mat) == 0 ? Ag[2*(h)+1] : Bg[2*(h)+1]) + (k0),          \
                    lp_ + qo[2*(h)+1]);                                       \
    } while (0)

#define READ_A(dst, Ab, hioff)                                                \
    _Pragma("unroll")                                                         \
    for (int i_ = 0; i_ < 4; i_++) {                                          \
        dst[i_][0] = *reinterpret_cast<const short8*>((Ab) + aoff + (hioff) + 1024 * i_ + pk0); \
        dst[i_][1] = *reinterpret_cast<const short8*>((Ab) + aoff + (hioff) + 1024 * i_ + pk1); \
    }
#define READ_B(dst, Bb, hioff)                                                \
    _Pragma("unroll")                                                         \
    for (int j_ = 0; j_ < 2; j_++) {                                          \
        dst[j_][0] = *reinterpret_cast<const short8*>((Bb) + boff + (hioff) + 1024 * j_ + pk0); \
        dst[j_][1] = *reinterpret_cast<const short8*>((Bb) + boff + (hioff) + 1024 * j_ + pk1); \
    }

#define MFMA16(qr, qc, Af, Bf)                                                \
    do {                                                                      \
        __builtin_amdgcn_s_setprio(1);                                        \
        _Pragma("unroll")                                                     \
        for (int ks_ = 0; ks_ < 2; ks_++)                                     \
            _Pragma("unroll")                                                 \
            for (int i_ = 0; i_ < 4; i_++)                                    \
                _Pragma("unroll")                                             \
                for (int j_ = 0; j_ < 2; j_++)                                \
                    acc[(qr) * 4 + i_][(qc) * 2 + j_] =                       \
                        __builtin_amdgcn_mfma_f32_16x16x32_bf16(              \
                            Af[i_][ks_], Bf[j_][ks_],                         \
                            acc[(qr) * 4 + i_][(qc) * 2 + j_], 0, 0, 0);      \
        __builtin_amdgcn_s_setprio(0);                                        \
    } while (0)

    short8 Alo[4][2], Ahi[4][2], Blo[2][2], Bhi[2][2];

    // ---- staging prologue: b0 all 4 halves (t=0), b1.Bh0/Bh1 (t=1) ----
    STAGE_HALF(0, 0, 0, 0);  STAGE_HALF(0, 0, 1, 0);
    STAGE_HALF(0, 1, 0, 0);  STAGE_HALF(0, 1, 1, 0);
    STAGE_HALF(1, 1, 0, 64); STAGE_HALF(1, 1, 1, 64);
    WVM4();                     // b0 landed; b1.Bh* may remain in flight
    BARX();

    const u16* A0b = &lds[0][0][0]; const u16* B0b = &lds[0][1][0];
    const u16* A1b = &lds[1][0][0]; const u16* B1b = &lds[1][1][0];

    for (int it = 0; it < NT / 2; ++it) {
        const int t0 = 2 * it;

        // ---- ph1: Q0 of t0 ----
        READ_A(Alo, A0b, 0);
        READ_B(Blo, B0b, 0);
        STAGE_HALF(1, 0, 0, (t0 + 1) * 64);            // b1.Ah0 <- t1
        WLG8();
        BARX(); WLG0();
        MFMA16(0, 0, Alo, Blo);
        BARX();

        // ---- ph2: Q1 of t0 ----
        READ_B(Bhi, B0b, 2048);
        STAGE_HALF(1, 0, 1, (t0 + 1) * 64);            // b1.Ah1 <- t1
        BARX(); WLG0();
        MFMA16(0, 1, Alo, Bhi);
        BARX();

        // ---- ph3: Q2 of t0 ----
        READ_A(Ahi, A0b, 4096);
        if (t0 + 2 < NT) STAGE_HALF(0, 1, 0, (t0 + 2) * 64);  // b0.Bh0 <- t0+2
        BARX(); WLG0();
        MFMA16(1, 0, Ahi, Blo);
        BARX();

        // ---- ph4: Q3 of t0 (no reads) ----
        if (t0 + 2 < NT) {
            STAGE_HALF(0, 1, 1, (t0 + 2) * 64);        // b0.Bh1
            WVM4();          // newest 4 = ph3/ph4's own stages; b1 landed
        } else {
            WVM0();          // no ph3/4 stages -> must drain b1.Ah*
        }
        BARX();
        MFMA16(1, 1, Ahi, Bhi);
        BARX();

        // ---- ph5: Q0 of t1 ----
        READ_A(Alo, A1b, 0);
        READ_B(Blo, B1b, 0);
        if (t0 + 2 < NT) STAGE_HALF(0, 0, 0, (t0 + 2) * 64);  // b0.Ah0
        WLG8();
        BARX(); WLG0();
        MFMA16(0, 0, Alo, Blo);
        BARX();

        // ---- ph6: Q1 of t1 ----
        READ_B(Bhi, B1b, 2048);
        if (t0 + 2 < NT) STAGE_HALF(0, 0, 1, (t0 + 2) * 64);  // b0.Ah1
        BARX(); WLG0();
        MFMA16(0, 1, Alo, Bhi);
        BARX();

        // ---- ph7: Q2 of t1 ----
        READ_A(Ahi, A1b, 4096);
        if (t0 + 3 < NT) STAGE_HALF(1, 1, 0, (t0 + 3) * 64);  // b1.Bh0 <- t1+2
        BARX(); WLG0();
        MFMA16(1, 0, Ahi, Blo);
        BARX();

        // ---- ph8: Q3 of t1 (no reads) ----
        if (t0 + 3 < NT) {
            STAGE_HALF(1, 1, 1, (t0 + 3) * 64);        // b1.Bh1
            WVM4();          // newest 4 = ph7/ph8's own; b0(t0+2) landed
        } else {
            WVM0();          // final iteration: drain
        }
        BARX();
        MFMA16(1, 1, Ahi, Bhi);
        BARX();
    }
    WVM0();   // drain any remaining staging DMA before epilogue/exit

#undef CFENCE
#undef BARX
#undef WLG0
#undef WLG8
#undef WVM4
#undef WVM0
#undef STAGE_HALF
#undef READ_A
#undef READ_B
#undef MFMA16

    // ---- epilogue. C/D layout: col=lane&15, row=quad*4+reg (m89/m91-verified) ----
    const int row0 = bm * 256 + wm + quad * 4;
    const int col0 = bn * 256 + wn + lr;
#pragma unroll
    for (int qr = 0; qr < 2; qr++)
#pragma unroll
        for (int i = 0; i < 4; i++)
#pragma unroll
            for (int qc = 0; qc < 2; qc++)
#pragma unroll
                for (int j = 0; j < 2; j++) {
                    const int col = col0 + qc * 32 + j * 16;
                    const float4v a = acc[qr * 4 + i][qc * 2 + j];
#pragma unroll
                    for (int r = 0; r < 4; r++) {
                        const int row = row0 + qr * 64 + i * 16 + r;
                        if (EPI == 0) {
                            const float rr = fmaxf(a[r], 0.f);
                            ((u16*)Cv)[(size_t)row * N + col] = f2bf(rr * rr);
                        } else {
                            ((float*)Cv)[(size_t)row * N + col] = a[r];
                        }
                    }
                }
}

// ---------- launch ----------

extern "C" void kernel_launch(void* const* d_in, const int* in_sizes, int n_in,
                              void* d_out, int out_size, void* d_ws, size_t ws_size,
                              hipStream_t stream) {
    const float* x      = (const float*)d_in[0];
    const float* fast_b = (const float*)d_in[1];
    const float* w_fc   = (const float*)d_in[2];
    const float* w_proj = (const float*)d_in[3];
    const float* u      = (const float*)d_in[4];
    const float* v      = (const float*)d_in[5];
    const float* gate   = (const float*)d_in[6];
    float* out = (float*)d_out;

    char* ws = (char*)d_ws;
    u16*   Xb  = (u16*)(ws + 0);                         // 16384*1024*2 = 32 MB
    u16*   W1  = (u16*)(ws + 33554432);                  // 4096*1024*2  =  8 MB
    u16*   W2  = (u16*)(ws + 41943040);                  // 1024*4096*2  =  8 MB
    u16*   RSQ = (u16*)(ws + 50331648);                  // 16384*4096*2 = 128 MB

    // fused prologue: W1 rows | W2 rows | x conversion
    prologue_kernel<<<HID + DIM + M_TOK * DIM / (256 * 4), 256, 0, stream>>>(
        x, w_fc, w_proj, u, fast_b, v, gate, Xb, W1, W2);

    // GEMM1: (16384,1024) @ (4096,1024)^T -> relu^2 bf16 (16384,4096); 1024 wgs
    gemm256<HID, DIM, 0><<<dim3((M_TOK / 256) * (HID / 256)), 512, 0, stream>>>(Xb, W1, RSQ);
    // GEMM2: (16384,4096) @ (1024,4096)^T -> fp32 out (16384,1024); 256 wgs
    gemm256<DIM, HID, 1><<<dim3((M_TOK / 256) * (DIM / 256)), 512, 0, stream>>>(RSQ, W2, out);
}